// Round 9
// baseline (216.992 us; speedup 1.0000x reference)
//
#include <hip/hip_runtime.h>
#include <hip/hip_bf16.h>
#include <math.h>

#define H_    16
#define DK_   64
#define Dm    1024
#define Bb    2
#define Ss    2048
#define Mrows 4096   // B*S
#define QSCALE 0.1803368801f   // (1/8) * log2(e): flash softmax runs in exp2 domain

typedef short s16x8 __attribute__((ext_vector_type(8)));
typedef float f32x4 __attribute__((ext_vector_type(4)));
typedef unsigned short u16;
typedef unsigned int u32;

__device__ __forceinline__ u16 f2b(float f) {
  __hip_bfloat16 h = __float2bfloat16(f);
  return *reinterpret_cast<u16*>(&h);
}
__device__ __forceinline__ float b2f(u16 u) {
  __hip_bfloat16 h;
  *reinterpret_cast<u16*>(&h) = u;
  return __bfloat162float(h);
}
// pack two fp32 -> (bf16(hi)<<16)|bf16(lo) by truncation: ONE v_perm_b32
__device__ __forceinline__ u32 pkbf(float hi, float lo) {
  return __builtin_amdgcn_perm(__float_as_uint(hi), __float_as_uint(lo), 0x07060302u);
}

// async global->LDS, 16B per lane; LDS dest = wave-uniform base + lane*16
#define GLDS(g, l)                                                             \
  __builtin_amdgcn_global_load_lds(                                            \
      (const __attribute__((address_space(1))) unsigned int*)(g),              \
      (__attribute__((address_space(3))) unsigned int*)(l), 16, 0, 0)

// XOR-swizzle for [rows][64] u16 tiles, 16B-chunk granular
__device__ __forceinline__ int SW64(int row, int col) {
  return row * 64 + ((((col >> 3) ^ (row & 7) ^ (row >> 3)) & 7) << 3) + (col & 7);
}

// ---------------------------------------------------------------- casts + rope table, one launch
__global__ __launch_bounds__(256) void k_castall(
    const float* __restrict__ x,  const float* __restrict__ Wq,
    const float* __restrict__ Wk, const float* __restrict__ Wv,
    const float* __restrict__ Wo,
    u16* __restrict__ xb,  u16* __restrict__ wqb, u16* __restrict__ wkb,
    u16* __restrict__ wvb, u16* __restrict__ wob,
    const int* __restrict__ pos, float2* __restrict__ tab) {
  if (blockIdx.x >= 8192) {
    int t = (blockIdx.x - 8192) * 256 + threadIdx.x;   // 65536
    int s = t >> 5, i = t & 31;
    float p = (float)pos[s];
    // 10000^(-i/32) = exp2(-i * log2(10000)/32): one trans op, no libm powf
    float ang = p * __builtin_amdgcn_exp2f(-(float)i * 0.4152448120604907f);
    tab[t] = make_float2(cosf(ang), sinf(ang));
    return;
  }
  int i = blockIdx.x * 256 + threadIdx.x;        // 2M float4 total
  const float* s;
  u16* d;
  int off;
  if (i < 1048576) { s = x; d = xb; off = i; }
  else {
    int j = i - 1048576;
    int w = j >> 18;
    off = j & 262143;
    s = (w == 0) ? Wq : (w == 1) ? Wk : (w == 2) ? Wv : Wo;
    d = (w == 0) ? wqb : (w == 1) ? wkb : (w == 2) ? wvb : wob;
  }
  float4 v = reinterpret_cast<const float4*>(s)[off];
  ushort4 o;
  o.x = f2b(v.x); o.y = f2b(v.y); o.z = f2b(v.z); o.w = f2b(v.w);
  reinterpret_cast<ushort4*>(d)[off] = o;
}

// ---------------------------------------------------------------- RoPE apply on K only
__global__ __launch_bounds__(256) void k_ropeK(u16* __restrict__ K,
                                               const float2* __restrict__ tab) {
  int t = blockIdx.x * 256 + threadIdx.x;        // Mrows*Dm/8
  int row = t >> 7;
  int c0 = (t & 127) << 3;
  int i0 = (c0 & 63) >> 1;
  const float2* tb = &tab[(row & (Ss - 1)) * 32 + i0];
  float2 cs[4];
#pragma unroll
  for (int j = 0; j < 4; ++j) cs[j] = tb[j];
  size_t off = (size_t)row * Dm + c0;
  s16x8 k = *reinterpret_cast<const s16x8*>(&K[off]);
  s16x8 ko;
#pragma unroll
  for (int j = 0; j < 4; ++j) {
    float ke = b2f((u16)k[2 * j]), kd = b2f((u16)k[2 * j + 1]);
    ko[2 * j]     = (short)f2b(cs[j].x * ke - cs[j].y * kd);
    ko[2 * j + 1] = (short)f2b(cs[j].y * ke + cs[j].x * kd);
  }
  *reinterpret_cast<s16x8*>(&K[off]) = ko;
}

// ---------------------------------------------------------------- C = A * B^T
// 128xBN tile, BK=32. RING-3 LDS + depth-2 prefetch + COUNTED vmcnt (T4).
// EPILOGUE-PACK (r8 theory): non-V blocks compute C^T via SWAPPED MFMA
// operands — mfma(bfr, af) gives lane = 4 consecutive output COLUMNS in the
// reg index (l16 = row), so Q/K store ushort4 (8B) and out-proj float4 (16B)
// instead of 64 scalar 2B/4B stores per thread (was ~30% of issue slots +
// 4x the store transactions). V^T blocks keep the original orientation
// (regs = 4 consecutive s, already packed).
// LDS: QKV 48 KB -> 3 blocks/CU; out-proj 36 KB -> 4 blocks/CU.
template <int BN, bool QKV>
__global__ __launch_bounds__(256) void k_gemm(
    const u16* __restrict__ A, const u16* __restrict__ B,
    u16* __restrict__ OQ, u16* __restrict__ OK2, u16* __restrict__ OVT,
    float* __restrict__ OF, int K) {
  constexpr int NFR = BN / 32;
  __shared__ __align__(16) u16 lsA[3][128 * 32];
  __shared__ __align__(16) u16 lsB[3][BN * 32];
  const int tid = threadIdx.x, lane = tid & 63, wave = tid >> 6;
  const int quad = lane >> 4, l16 = lane & 15;
  const int wrow = wave >> 1, wcol = wave & 1;
  const int n0 = blockIdx.x * BN, m0 = blockIdx.y * 128;
  const bool vblk = QKV && (n0 >> 10) == 2;   // V-block: keep normal orientation
  f32x4 acc[4][NFR] = {};

  auto stage = [&](int k0, int bi) {
    // A tile 128x32: 512 16B chunks, 2 per thread
#pragma unroll
    for (int c = 0; c < 2; ++c) {
      int f = (wave * 2 + c) * 64 + lane;
      int row = f >> 2;
      int gs = (f & 3) ^ ((row >> 1) & 3);
      GLDS(A + (size_t)(m0 + row) * K + k0 + gs * 8, &lsA[bi][(wave * 2 + c) * 512]);
    }
    // B tile BNx32: BN*4 chunks, NFR/2 per thread
#pragma unroll
    for (int c = 0; c < NFR / 2; ++c) {
      int f = (wave * (NFR / 2) + c) * 64 + lane;
      int row = f >> 2;
      int gs = (f & 3) ^ ((row >> 1) & 3);
      GLDS(B + (size_t)(n0 + row) * K + k0 + gs * 8, &lsB[bi][(wave * (NFR / 2) + c) * 512]);
    }
  };

  stage(0, 0);
  stage(32, 1);
  int bi = 0, stg = 2;
  for (int k0 = 0; k0 < K; k0 += 32) {
    if (k0 + 32 < K) {
      // retire tile t (its LOADS=2+NFR/2 GLDS per thread), keep t+1 in flight
      if constexpr (NFR == 4) asm volatile("s_waitcnt vmcnt(4)" ::: "memory");
      else                    asm volatile("s_waitcnt vmcnt(3)" ::: "memory");
    } else {
      asm volatile("s_waitcnt vmcnt(0)" ::: "memory");
    }
    __builtin_amdgcn_sched_barrier(0);
    __builtin_amdgcn_s_barrier();
    if (k0 + 64 < K) stage(k0 + 64, stg);
    s16x8 af[4], bfr[NFR];
#pragma unroll
    for (int i = 0; i < 4; ++i) {
      int row = wrow * 64 + i * 16 + l16;
      af[i] = *reinterpret_cast<const s16x8*>(
          &lsA[bi][row * 32 + ((quad ^ ((row >> 1) & 3)) << 3)]);
    }
#pragma unroll
    for (int i = 0; i < NFR; ++i) {
      int row = wcol * (BN / 2) + i * 16 + l16;
      bfr[i] = *reinterpret_cast<const s16x8*>(
          &lsB[bi][row * 32 + ((quad ^ ((row >> 1) & 3)) << 3)]);
    }
    if (vblk) {
#pragma unroll
      for (int mi = 0; mi < 4; ++mi)
#pragma unroll
        for (int ni = 0; ni < NFR; ++ni)
          acc[mi][ni] = __builtin_amdgcn_mfma_f32_16x16x32_bf16(af[mi], bfr[ni], acc[mi][ni], 0, 0, 0);
    } else {
      // swapped: acc[mi][ni] = C^T fragment; lane l16 = m-row, regs = 4 n-cols
#pragma unroll
      for (int mi = 0; mi < 4; ++mi)
#pragma unroll
        for (int ni = 0; ni < NFR; ++ni)
          acc[mi][ni] = __builtin_amdgcn_mfma_f32_16x16x32_bf16(bfr[ni], af[mi], acc[mi][ni], 0, 0, 0);
    }
    stg = bi;
    bi = (bi == 2) ? 0 : bi + 1;
  }

  if (QKV) {
    const int which = n0 >> 10;          // tiles never straddle a 1024 boundary
    const int nbase = (n0 & 1023) + wcol * (BN / 2);
    if (which == 2) {
      // V^T: normal orientation, regs = 4 consecutive s -> 8B stores
#pragma unroll
      for (int mi = 0; mi < 4; ++mi)
#pragma unroll
        for (int ni = 0; ni < NFR; ++ni) {
          int row0 = m0 + wrow * 64 + mi * 16 + quad * 4;
          int col  = nbase + ni * 16 + l16;
          int bb = row0 >> 11, s0 = row0 & (Ss - 1);
          ushort4 pk;
          pk.x = f2b(acc[mi][ni][0]); pk.y = f2b(acc[mi][ni][1]);
          pk.z = f2b(acc[mi][ni][2]); pk.w = f2b(acc[mi][ni][3]);
          *reinterpret_cast<ushort4*>(&OVT[((size_t)bb * Dm + col) * Ss + s0]) = pk;
        }
    } else {
      // Q/K: swapped orientation, regs = 4 consecutive n-cols -> 8B stores
      u16* Op = which ? OK2 : OQ;
#pragma unroll
      for (int mi = 0; mi < 4; ++mi)
#pragma unroll
        for (int ni = 0; ni < NFR; ++ni) {
          int row = m0 + wrow * 64 + mi * 16 + l16;
          int col = nbase + ni * 16 + quad * 4;
          ushort4 pk;
          pk.x = f2b(acc[mi][ni][0]); pk.y = f2b(acc[mi][ni][1]);
          pk.z = f2b(acc[mi][ni][2]); pk.w = f2b(acc[mi][ni][3]);
          *reinterpret_cast<ushort4*>(&Op[(size_t)row * Dm + col]) = pk;
        }
    }
  } else {
    // out-proj fp32: swapped orientation -> float4 (16B) stores
#pragma unroll
    for (int mi = 0; mi < 4; ++mi)
#pragma unroll
      for (int ni = 0; ni < NFR; ++ni) {
        int row = m0 + wrow * 64 + mi * 16 + l16;
        int col = n0 + wcol * (BN / 2) + ni * 16 + quad * 4;
        *reinterpret_cast<f32x4*>(&OF[(size_t)row * Dm + col]) = acc[mi][ni];
      }
  }
}

// ---------------------------------------------------------------- flash attention (causal)
// Transposed compute: S^T = K Q^T, O^T = V^T P^T. Static-max softmax, exp2
// domain, Q-RoPE fused into the fragment load. 16 q/wave, QBLK=64 (4 waves),
// grid 1024 blocks, 40 KB LDS -> 4 blocks/CU. (r8: occupancy 21%, 45.5us —
// same wall as 32q/wave at 12%: per-wave LDS K/V read is the invariant.)
__global__ __launch_bounds__(256) void k_flash(const u16* __restrict__ Q,
                                               const u16* __restrict__ K,
                                               const u16* __restrict__ VT,
                                               u16* __restrict__ O,
                                               const float2* __restrict__ tab) {
  __shared__ __align__(16) u16 lsK[2][64 * 64];    // [slot][key][dk], SW64
  __shared__ __align__(16) u16 lsVT[2][64 * 64];   // [slot][dk][key], SW64
  __shared__ __align__(16) u16 lsP[4][16 * 64];    // per-wave P^T [q][key], chunk-xor
  const int tid = threadIdx.x, lane = tid & 63, wave = tid >> 6;
  const int quad = lane >> 4, l16 = lane & 15;
  const int bid = blockIdx.x;                      // 1024 blocks
  const int bh = bid & 31;
  const int h = bh & (H_ - 1), b = bh >> 4;
  const int g = bid >> 5, a = g & 15, bsel = g >> 4;
  const int qt = bsel ? (31 - a) : a;              // balanced causal map (64-q tiles)
  const int qbase = qt * 64 + wave * 16;
  const int xorv = (l16 * 2) & 0xE;

  // Q frag with fused RoPE (+QSCALE): q row = qbase+l16, 8 dk per kc chunk
  s16x8 qf[2];
  {
    const int qpos = qbase + l16;
    const size_t qoff = (size_t)(b * Ss + qpos) * Dm + h * 64;
    s16x8 r0 = *reinterpret_cast<const s16x8*>(&Q[qoff + quad * 8]);
    s16x8 r1 = *reinterpret_cast<const s16x8*>(&Q[qoff + 32 + quad * 8]);
    const float2* tb = &tab[qpos * 32];
#pragma unroll
    for (int kc = 0; kc < 2; ++kc) {
      s16x8 raw = kc ? r1 : r0;
#pragma unroll
      for (int p = 0; p < 4; ++p) {
        float2 cs = tb[kc * 16 + quad * 4 + p];
        float e = b2f((u16)raw[2 * p]), o = b2f((u16)raw[2 * p + 1]);
        qf[kc][2 * p]     = (short)f2b((cs.x * e - cs.y * o) * QSCALE);
        qf[kc][2 * p + 1] = (short)f2b((cs.y * e + cs.x * o) * QSCALE);
      }
    }
  }
  s16x8 ones;
#pragma unroll
  for (int j = 0; j < 8; ++j) ones[j] = (short)0x3F80;   // bf16 1.0

  f32x4 ot[4] = {};
  f32x4 lAcc = {};

  auto stage1 = [&](int kt) {
    const int slot = kt & 1;
    const size_t kbase  = (size_t)(b * Ss + kt * 64) * Dm + h * 64;
    const size_t vtbase = ((size_t)b * Dm + h * 64) * Ss + kt * 64;
#pragma unroll
    for (int c = 0; c < 2; ++c) {
      int sl = (wave * 2 + c) * 64 + lane;
      int row = sl >> 3;
      int gg = ((sl & 7) ^ (row & 7) ^ (row >> 3)) & 7;
      GLDS(K  + kbase  + (size_t)row * Dm + gg * 8, &lsK[slot][(wave * 2 + c) * 512]);
      GLDS(VT + vtbase + (size_t)row * Ss + gg * 8, &lsVT[slot][(wave * 2 + c) * 512]);
    }
  };

  const int ktend = qt + 1;
  stage1(0);
  for (int kt = 0; kt < ktend; ++kt) {
    __syncthreads();
    if (kt + 1 < ktend) stage1(kt + 1);
    const int slot = kt & 1;

    f32x4 st[4] = {};
#pragma unroll
    for (int kc = 0; kc < 2; ++kc)
#pragma unroll
      for (int ni = 0; ni < 4; ++ni) {
        s16x8 kf = *reinterpret_cast<const s16x8*>(
            &lsK[slot][SW64(ni * 16 + l16, kc * 32 + quad * 8)]);
        st[ni] = __builtin_amdgcn_mfma_f32_16x16x32_bf16(kf, qf[kc], st[ni], 0, 0, 0);
      }

    if (kt == qt) {   // diagonal tile (wave-uniform): mask key > q
      int gq = qbase + l16;
#pragma unroll
      for (int ni = 0; ni < 4; ++ni)
#pragma unroll
        for (int r = 0; r < 4; ++r)
          if (kt * 64 + ni * 16 + quad * 4 + r > gq) st[ni][r] = -INFINITY;
    }
#pragma unroll
    for (int ni = 0; ni < 4; ++ni) {
      float e0 = __builtin_amdgcn_exp2f(st[ni][0]);
      float e1 = __builtin_amdgcn_exp2f(st[ni][1]);
      float e2 = __builtin_amdgcn_exp2f(st[ni][2]);
      float e3 = __builtin_amdgcn_exp2f(st[ni][3]);
      uint2 pk;
      pk.x = pkbf(e1, e0);
      pk.y = pkbf(e3, e2);
      *reinterpret_cast<uint2*>(
          &lsP[wave][l16 * 64 + (((ni * 4 + quad) ^ xorv) << 2)]) = pk;
    }
#pragma unroll
    for (int kc = 0; kc < 2; ++kc) {
      s16x8 pf = *reinterpret_cast<const s16x8*>(
          &lsP[wave][l16 * 64 + (((kc * 8 + quad * 2) ^ xorv) << 2)]);
      lAcc = __builtin_amdgcn_mfma_f32_16x16x32_bf16(ones, pf, lAcc, 0, 0, 0);
#pragma unroll
      for (int ni = 0; ni < 4; ++ni) {
        s16x8 vf = *reinterpret_cast<const s16x8*>(
            &lsVT[slot][SW64(ni * 16 + l16, kc * 32 + quad * 8)]);
        ot[ni] = __builtin_amdgcn_mfma_f32_16x16x32_bf16(vf, pf, ot[ni], 0, 0, 0);
      }
    }
  }

  // epilogue: O[q][dk], 4 consecutive dk per lane -> 8B stores
  {
    float inv = 1.0f / lAcc[0];
    const size_t obase = (size_t)(b * Ss + qbase + l16) * Dm + h * 64;
#pragma unroll
    for (int ni = 0; ni < 4; ++ni) {
      ushort4 pk;
      pk.x = f2b(ot[ni][0] * inv); pk.y = f2b(ot[ni][1] * inv);
      pk.z = f2b(ot[ni][2] * inv); pk.w = f2b(ot[ni][3] * inv);
      *reinterpret_cast<ushort4*>(&O[obase + ni * 16 + quad * 4]) = pk;
    }
  }
}

// ---------------------------------------------------------------- launch
extern "C" void kernel_launch(void* const* d_in, const int* in_sizes, int n_in,
                              void* d_out, int out_size, void* d_ws, size_t ws_size,
                              hipStream_t stream) {
  const float* x  = (const float*)d_in[0];
  const float* Wq = (const float*)d_in[1];
  const float* Wk = (const float*)d_in[2];
  const float* Wv = (const float*)d_in[3];
  const float* Wo = (const float*)d_in[4];
  const int* pos  = (const int*)d_in[5];
  float* out = (float*)d_out;

  char* w = (char*)d_ws;
  u16* xb  = (u16*)w; w += (size_t)Mrows * Dm * 2;
  u16* wqb = (u16*)w; w += (size_t)Dm * Dm * 2;   // wqb/wkb/wvb contiguous:
  u16* wkb = (u16*)w; w += (size_t)Dm * Dm * 2;   // merged [3072][1024] B matrix
  u16* wvb = (u16*)w; w += (size_t)Dm * Dm * 2;
  u16* wob = (u16*)w; w += (size_t)Dm * Dm * 2;
  u16* Qb  = (u16*)w; w += (size_t)Mrows * Dm * 2;
  u16* Kb  = (u16*)w; w += (size_t)Mrows * Dm * 2;
  u16* VTb = (u16*)w; w += (size_t)Mrows * Dm * 2;   // V transposed [b][e][s]
  u16* Ab  = (u16*)w; w += (size_t)Mrows * Dm * 2;
  float2* tabf = (float2*)w; w += (size_t)Ss * 32 * sizeof(float2);

  // casts + rope table in one launch
  k_castall<<<8448, 256, 0, stream>>>(x, Wq, Wk, Wv, Wo, xb, wqb, wkb, wvb, wob,
                                      pos, tabf);
  // merged QKV projection: B=[3072][1024], epilogue routes Q/K/V^T by n-tile
  k_gemm<128, true><<<dim3(24, 32), 256, 0, stream>>>(xb, wqb, Qb, Kb, VTb, nullptr, Dm);
  // RoPE on K only (Q's RoPE fused into flash)
  k_ropeK<<<Mrows * Dm / 8 / 256, 256, 0, stream>>>(Kb, tabf);
  k_flash<<<dim3(1024), 256, 0, stream>>>(Qb, Kb, VTb, Ab, tabf);
  // output projection, fp32 epilogue
  k_gemm<64, false><<<dim3(16, 32), 256, 0, stream>>>(Ab, wob, nullptr, nullptr, nullptr, out, Dm);
}

// Round 10
// 189.021 us; speedup vs baseline: 1.1480x; 1.1480x over previous
//
#include <hip/hip_runtime.h>
#include <hip/hip_bf16.h>
#include <math.h>

#define H_    16
#define DK_   64
#define Dm    1024
#define Bb    2
#define Ss    2048
#define Mrows 4096   // B*S
#define QSCALE 0.1803368801f   // (1/8) * log2(e): flash softmax runs in exp2 domain

typedef short s16x8 __attribute__((ext_vector_type(8)));
typedef float f32x4 __attribute__((ext_vector_type(4)));
typedef unsigned short u16;
typedef unsigned int u32;

__device__ __forceinline__ u16 f2b(float f) {
  __hip_bfloat16 h = __float2bfloat16(f);
  return *reinterpret_cast<u16*>(&h);
}
__device__ __forceinline__ float b2f(u16 u) {
  __hip_bfloat16 h;
  *reinterpret_cast<u16*>(&h) = u;
  return __bfloat162float(h);
}
// pack two fp32 -> (bf16(hi)<<16)|bf16(lo) by truncation: ONE v_perm_b32
__device__ __forceinline__ u32 pkbf(float hi, float lo) {
  return __builtin_amdgcn_perm(__float_as_uint(hi), __float_as_uint(lo), 0x07060302u);
}

// async global->LDS, 16B per lane; LDS dest = wave-uniform base + lane*16
#define GLDS(g, l)                                                             \
  __builtin_amdgcn_global_load_lds(                                            \
      (const __attribute__((address_space(1))) unsigned int*)(g),              \
      (__attribute__((address_space(3))) unsigned int*)(l), 16, 0, 0)

// XOR-swizzle for [rows][64] u16 tiles, 16B-chunk granular
__device__ __forceinline__ int SW64(int row, int col) {
  return row * 64 + ((((col >> 3) ^ (row & 7) ^ (row >> 3)) & 7) << 3) + (col & 7);
}

// ---------------------------------------------------------------- casts + rope table, one launch
__global__ __launch_bounds__(256) void k_castall(
    const float* __restrict__ x,  const float* __restrict__ Wq,
    const float* __restrict__ Wk, const float* __restrict__ Wv,
    const float* __restrict__ Wo,
    u16* __restrict__ xb,  u16* __restrict__ wqb, u16* __restrict__ wkb,
    u16* __restrict__ wvb, u16* __restrict__ wob,
    const int* __restrict__ pos, float2* __restrict__ tab) {
  if (blockIdx.x >= 8192) {
    int t = (blockIdx.x - 8192) * 256 + threadIdx.x;   // 65536
    int s = t >> 5, i = t & 31;
    float p = (float)pos[s];
    // 10000^(-i/32) = exp2(-i * log2(10000)/32): one trans op, no libm powf
    float ang = p * __builtin_amdgcn_exp2f(-(float)i * 0.4152448120604907f);
    tab[t] = make_float2(cosf(ang), sinf(ang));
    return;
  }
  int i = blockIdx.x * 256 + threadIdx.x;        // 2M float4 total
  const float* s;
  u16* d;
  int off;
  if (i < 1048576) { s = x; d = xb; off = i; }
  else {
    int j = i - 1048576;
    int w = j >> 18;
    off = j & 262143;
    s = (w == 0) ? Wq : (w == 1) ? Wk : (w == 2) ? Wv : Wo;
    d = (w == 0) ? wqb : (w == 1) ? wkb : (w == 2) ? wvb : wob;
  }
  float4 v = reinterpret_cast<const float4*>(s)[off];
  ushort4 o;
  o.x = f2b(v.x); o.y = f2b(v.y); o.z = f2b(v.z); o.w = f2b(v.w);
  reinterpret_cast<ushort4*>(d)[off] = o;
}

// ---------------------------------------------------------------- RoPE apply on K only
__global__ __launch_bounds__(256) void k_ropeK(u16* __restrict__ K,
                                               const float2* __restrict__ tab) {
  int t = blockIdx.x * 256 + threadIdx.x;        // Mrows*Dm/8
  int row = t >> 7;
  int c0 = (t & 127) << 3;
  int i0 = (c0 & 63) >> 1;
  const float2* tb = &tab[(row & (Ss - 1)) * 32 + i0];
  float2 cs[4];
#pragma unroll
  for (int j = 0; j < 4; ++j) cs[j] = tb[j];
  size_t off = (size_t)row * Dm + c0;
  s16x8 k = *reinterpret_cast<const s16x8*>(&K[off]);
  s16x8 ko;
#pragma unroll
  for (int j = 0; j < 4; ++j) {
    float ke = b2f((u16)k[2 * j]), kd = b2f((u16)k[2 * j + 1]);
    ko[2 * j]     = (short)f2b(cs[j].x * ke - cs[j].y * kd);
    ko[2 * j + 1] = (short)f2b(cs[j].y * ke + cs[j].x * kd);
  }
  *reinterpret_cast<s16x8*>(&K[off]) = ko;
}

// ---------------------------------------------------------------- C = A * B^T
// 128xBN tile, BK=32. RING-3 LDS + depth-2 prefetch + COUNTED vmcnt (T4):
// per K-step, wait vmcnt(LOADS) (retires tile t, leaves tile t+1 in flight),
// raw s_barrier (no compiler vmcnt(0) drain), issue tile t+2's GLDS, then
// ds_read + MFMA. (r6-proven: QKV <46us. r9 lesson: NEVER perturb this main
// loop — the operand-swap variant added per-iter accumulator copies, +25us.)
// LDS: BN=128 48 KB; BN=64 36 KB.
template <int BN, bool QKV>
__global__ __launch_bounds__(256) void k_gemm(
    const u16* __restrict__ A, const u16* __restrict__ B,
    u16* __restrict__ OQ, u16* __restrict__ OK2, u16* __restrict__ OVT,
    float* __restrict__ OF, int K) {
  constexpr int NFR = BN / 32;
  __shared__ __align__(16) u16 lsA[3][128 * 32];
  __shared__ __align__(16) u16 lsB[3][BN * 32];
  const int tid = threadIdx.x, lane = tid & 63, wave = tid >> 6;
  const int quad = lane >> 4, l16 = lane & 15;
  const int wrow = wave >> 1, wcol = wave & 1;
  const int n0 = blockIdx.x * BN, m0 = blockIdx.y * 128;
  f32x4 acc[4][NFR] = {};

  auto stage = [&](int k0, int bi) {
    // A tile 128x32: 512 16B chunks, 2 per thread
#pragma unroll
    for (int c = 0; c < 2; ++c) {
      int f = (wave * 2 + c) * 64 + lane;
      int row = f >> 2;
      int gs = (f & 3) ^ ((row >> 1) & 3);
      GLDS(A + (size_t)(m0 + row) * K + k0 + gs * 8, &lsA[bi][(wave * 2 + c) * 512]);
    }
    // B tile BNx32: BN*4 chunks, NFR/2 per thread
#pragma unroll
    for (int c = 0; c < NFR / 2; ++c) {
      int f = (wave * (NFR / 2) + c) * 64 + lane;
      int row = f >> 2;
      int gs = (f & 3) ^ ((row >> 1) & 3);
      GLDS(B + (size_t)(n0 + row) * K + k0 + gs * 8, &lsB[bi][(wave * (NFR / 2) + c) * 512]);
    }
  };

  stage(0, 0);
  stage(32, 1);
  int bi = 0, stg = 2;
  for (int k0 = 0; k0 < K; k0 += 32) {
    if (k0 + 32 < K) {
      // retire tile t (its LOADS=2+NFR/2 GLDS per thread), keep t+1 in flight
      if constexpr (NFR == 4) asm volatile("s_waitcnt vmcnt(4)" ::: "memory");
      else                    asm volatile("s_waitcnt vmcnt(3)" ::: "memory");
    } else {
      asm volatile("s_waitcnt vmcnt(0)" ::: "memory");
    }
    __builtin_amdgcn_sched_barrier(0);
    __builtin_amdgcn_s_barrier();
    if (k0 + 64 < K) stage(k0 + 64, stg);
    s16x8 af[4], bfr[NFR];
#pragma unroll
    for (int i = 0; i < 4; ++i) {
      int row = wrow * 64 + i * 16 + l16;
      af[i] = *reinterpret_cast<const s16x8*>(
          &lsA[bi][row * 32 + ((quad ^ ((row >> 1) & 3)) << 3)]);
    }
#pragma unroll
    for (int i = 0; i < NFR; ++i) {
      int row = wcol * (BN / 2) + i * 16 + l16;
      bfr[i] = *reinterpret_cast<const s16x8*>(
          &lsB[bi][row * 32 + ((quad ^ ((row >> 1) & 3)) << 3)]);
    }
#pragma unroll
    for (int mi = 0; mi < 4; ++mi)
#pragma unroll
      for (int ni = 0; ni < NFR; ++ni)
        acc[mi][ni] = __builtin_amdgcn_mfma_f32_16x16x32_bf16(af[mi], bfr[ni], acc[mi][ni], 0, 0, 0);
    stg = bi;
    bi = (bi == 2) ? 0 : bi + 1;
  }

  if (QKV) {
    const int which = n0 >> 10;          // tiles never straddle a 1024 boundary
    const int nbase = (n0 & 1023) + wcol * (BN / 2);
    if (which == 2) {
#pragma unroll
      for (int mi = 0; mi < 4; ++mi)
#pragma unroll
        for (int ni = 0; ni < NFR; ++ni) {
          int row0 = m0 + wrow * 64 + mi * 16 + quad * 4;
          int col  = nbase + ni * 16 + l16;
          int bb = row0 >> 11, s0 = row0 & (Ss - 1);
          ushort4 pk;
          pk.x = f2b(acc[mi][ni][0]); pk.y = f2b(acc[mi][ni][1]);
          pk.z = f2b(acc[mi][ni][2]); pk.w = f2b(acc[mi][ni][3]);
          *reinterpret_cast<ushort4*>(&OVT[((size_t)bb * Dm + col) * Ss + s0]) = pk;
        }
    } else {
      u16* Op = which ? OK2 : OQ;
#pragma unroll
      for (int mi = 0; mi < 4; ++mi)
#pragma unroll
        for (int ni = 0; ni < NFR; ++ni)
#pragma unroll
          for (int r = 0; r < 4; ++r) {
            int row = m0 + wrow * 64 + mi * 16 + quad * 4 + r;
            int col = nbase + ni * 16 + l16;
            Op[(size_t)row * Dm + col] = f2b(acc[mi][ni][r]);
          }
    }
  } else {
#pragma unroll
    for (int mi = 0; mi < 4; ++mi)
#pragma unroll
      for (int ni = 0; ni < NFR; ++ni)
#pragma unroll
        for (int r = 0; r < 4; ++r) {
          int row = m0 + wrow * 64 + mi * 16 + quad * 4 + r;
          int col = n0 + wcol * (BN / 2) + ni * 16 + l16;
          OF[(size_t)row * Dm + col] = acc[mi][ni][r];
        }
  }
}

// ---------------------------------------------------------------- flash attention (causal)
// Transposed compute: S^T = K Q^T, O^T = V^T P^T. Static-max softmax, exp2
// domain, Q-RoPE fused into the fragment load. 16 q/wave, QBLK=64 (4 waves),
// grid 1024 blocks, 40 KB LDS -> 4 blocks/CU. (r8: occupancy 21%, 45.5us —
// same wall as 32q/wave at 12%: per-wave LDS K/V read is the invariant.)
__global__ __launch_bounds__(256) void k_flash(const u16* __restrict__ Q,
                                               const u16* __restrict__ K,
                                               const u16* __restrict__ VT,
                                               u16* __restrict__ O,
                                               const float2* __restrict__ tab) {
  __shared__ __align__(16) u16 lsK[2][64 * 64];    // [slot][key][dk], SW64
  __shared__ __align__(16) u16 lsVT[2][64 * 64];   // [slot][dk][key], SW64
  __shared__ __align__(16) u16 lsP[4][16 * 64];    // per-wave P^T [q][key], chunk-xor
  const int tid = threadIdx.x, lane = tid & 63, wave = tid >> 6;
  const int quad = lane >> 4, l16 = lane & 15;
  const int bid = blockIdx.x;                      // 1024 blocks
  const int bh = bid & 31;
  const int h = bh & (H_ - 1), b = bh >> 4;
  const int g = bid >> 5, a = g & 15, bsel = g >> 4;
  const int qt = bsel ? (31 - a) : a;              // balanced causal map (64-q tiles)
  const int qbase = qt * 64 + wave * 16;
  const int xorv = (l16 * 2) & 0xE;

  // Q frag with fused RoPE (+QSCALE): q row = qbase+l16, 8 dk per kc chunk
  s16x8 qf[2];
  {
    const int qpos = qbase + l16;
    const size_t qoff = (size_t)(b * Ss + qpos) * Dm + h * 64;
    s16x8 r0 = *reinterpret_cast<const s16x8*>(&Q[qoff + quad * 8]);
    s16x8 r1 = *reinterpret_cast<const s16x8*>(&Q[qoff + 32 + quad * 8]);
    const float2* tb = &tab[qpos * 32];
#pragma unroll
    for (int kc = 0; kc < 2; ++kc) {
      s16x8 raw = kc ? r1 : r0;
#pragma unroll
      for (int p = 0; p < 4; ++p) {
        float2 cs = tb[kc * 16 + quad * 4 + p];
        float e = b2f((u16)raw[2 * p]), o = b2f((u16)raw[2 * p + 1]);
        qf[kc][2 * p]     = (short)f2b((cs.x * e - cs.y * o) * QSCALE);
        qf[kc][2 * p + 1] = (short)f2b((cs.y * e + cs.x * o) * QSCALE);
      }
    }
  }
  s16x8 ones;
#pragma unroll
  for (int j = 0; j < 8; ++j) ones[j] = (short)0x3F80;   // bf16 1.0

  f32x4 ot[4] = {};
  f32x4 lAcc = {};

  auto stage1 = [&](int kt) {
    const int slot = kt & 1;
    const size_t kbase  = (size_t)(b * Ss + kt * 64) * Dm + h * 64;
    const size_t vtbase = ((size_t)b * Dm + h * 64) * Ss + kt * 64;
#pragma unroll
    for (int c = 0; c < 2; ++c) {
      int sl = (wave * 2 + c) * 64 + lane;
      int row = sl >> 3;
      int gg = ((sl & 7) ^ (row & 7) ^ (row >> 3)) & 7;
      GLDS(K  + kbase  + (size_t)row * Dm + gg * 8, &lsK[slot][(wave * 2 + c) * 512]);
      GLDS(VT + vtbase + (size_t)row * Ss + gg * 8, &lsVT[slot][(wave * 2 + c) * 512]);
    }
  };

  const int ktend = qt + 1;
  stage1(0);
  for (int kt = 0; kt < ktend; ++kt) {
    __syncthreads();
    if (kt + 1 < ktend) stage1(kt + 1);
    const int slot = kt & 1;

    f32x4 st[4] = {};
#pragma unroll
    for (int kc = 0; kc < 2; ++kc)
#pragma unroll
      for (int ni = 0; ni < 4; ++ni) {
        s16x8 kf = *reinterpret_cast<const s16x8*>(
            &lsK[slot][SW64(ni * 16 + l16, kc * 32 + quad * 8)]);
        st[ni] = __builtin_amdgcn_mfma_f32_16x16x32_bf16(kf, qf[kc], st[ni], 0, 0, 0);
      }

    if (kt == qt) {   // diagonal tile (wave-uniform): mask key > q
      int gq = qbase + l16;
#pragma unroll
      for (int ni = 0; ni < 4; ++ni)
#pragma unroll
        for (int r = 0; r < 4; ++r)
          if (kt * 64 + ni * 16 + quad * 4 + r > gq) st[ni][r] = -INFINITY;
    }
#pragma unroll
    for (int ni = 0; ni < 4; ++ni) {
      float e0 = __builtin_amdgcn_exp2f(st[ni][0]);
      float e1 = __builtin_amdgcn_exp2f(st[ni][1]);
      float e2 = __builtin_amdgcn_exp2f(st[ni][2]);
      float e3 = __builtin_amdgcn_exp2f(st[ni][3]);
      uint2 pk;
      pk.x = pkbf(e1, e0);
      pk.y = pkbf(e3, e2);
      *reinterpret_cast<uint2*>(
          &lsP[wave][l16 * 64 + (((ni * 4 + quad) ^ xorv) << 2)]) = pk;
    }
#pragma unroll
    for (int kc = 0; kc < 2; ++kc) {
      s16x8 pf = *reinterpret_cast<const s16x8*>(
          &lsP[wave][l16 * 64 + (((kc * 8 + quad * 2) ^ xorv) << 2)]);
      lAcc = __builtin_amdgcn_mfma_f32_16x16x32_bf16(ones, pf, lAcc, 0, 0, 0);
#pragma unroll
      for (int ni = 0; ni < 4; ++ni) {
        s16x8 vf = *reinterpret_cast<const s16x8*>(
            &lsVT[slot][SW64(ni * 16 + l16, kc * 32 + quad * 8)]);
        ot[ni] = __builtin_amdgcn_mfma_f32_16x16x32_bf16(vf, pf, ot[ni], 0, 0, 0);
      }
    }
  }

  // epilogue: O[q][dk], 4 consecutive dk per lane -> 8B stores
  {
    float inv = 1.0f / lAcc[0];
    const size_t obase = (size_t)(b * Ss + qbase + l16) * Dm + h * 64;
#pragma unroll
    for (int ni = 0; ni < 4; ++ni) {
      ushort4 pk;
      pk.x = f2b(ot[ni][0] * inv); pk.y = f2b(ot[ni][1] * inv);
      pk.z = f2b(ot[ni][2] * inv); pk.w = f2b(ot[ni][3] * inv);
      *reinterpret_cast<ushort4*>(&O[obase + ni * 16 + quad * 4]) = pk;
    }
  }
}

// ---------------------------------------------------------------- launch
extern "C" void kernel_launch(void* const* d_in, const int* in_sizes, int n_in,
                              void* d_out, int out_size, void* d_ws, size_t ws_size,
                              hipStream_t stream) {
  const float* x  = (const float*)d_in[0];
  const float* Wq = (const float*)d_in[1];
  const float* Wk = (const float*)d_in[2];
  const float* Wv = (const float*)d_in[3];
  const float* Wo = (const float*)d_in[4];
  const int* pos  = (const int*)d_in[5];
  float* out = (float*)d_out;

  char* w = (char*)d_ws;
  u16* xb  = (u16*)w; w += (size_t)Mrows * Dm * 2;
  u16* wqb = (u16*)w; w += (size_t)Dm * Dm * 2;   // wqb/wkb/wvb contiguous:
  u16* wkb = (u16*)w; w += (size_t)Dm * Dm * 2;   // merged [3072][1024] B matrix
  u16* wvb = (u16*)w; w += (size_t)Dm * Dm * 2;
  u16* wob = (u16*)w; w += (size_t)Dm * Dm * 2;
  u16* Qb  = (u16*)w; w += (size_t)Mrows * Dm * 2;
  u16* Kb  = (u16*)w; w += (size_t)Mrows * Dm * 2;
  u16* VTb = (u16*)w; w += (size_t)Mrows * Dm * 2;   // V transposed [b][e][s]
  u16* Ab  = (u16*)w; w += (size_t)Mrows * Dm * 2;
  float2* tabf = (float2*)w; w += (size_t)Ss * 32 * sizeof(float2);

  // casts + rope table in one launch
  k_castall<<<8448, 256, 0, stream>>>(x, Wq, Wk, Wv, Wo, xb, wqb, wkb, wvb, wob,
                                      pos, tabf);
  // merged QKV projection: B=[3072][1024], epilogue routes Q/K/V^T by n-tile
  k_gemm<128, true><<<dim3(24, 32), 256, 0, stream>>>(xb, wqb, Qb, Kb, VTb, nullptr, Dm);
  // RoPE on K only (Q's RoPE fused into flash)
  k_ropeK<<<Mrows * Dm / 8 / 256, 256, 0, stream>>>(Kb, tabf);
  k_flash<<<dim3(1024), 256, 0, stream>>>(Qb, Kb, VTb, Ab, tabf);
  // output projection, fp32 epilogue: 128x128 tile (was BN=64 — NFR=2 halves
  // MFMA:ds_read density; the 128^2 tile is the QKV-proven configuration)
  k_gemm<128, false><<<dim3(8, 32), 256, 0, stream>>>(Ab, wob, nullptr, nullptr, nullptr, out, Dm);
}

// Round 11
// 186.733 us; speedup vs baseline: 1.1620x; 1.0123x over previous
//
#include <hip/hip_runtime.h>
#include <hip/hip_bf16.h>
#include <math.h>

#define H_    16
#define DK_   64
#define Dm    1024
#define Bb    2
#define Ss    2048
#define Mrows 4096   // B*S
#define QSCALE 0.1803368801f   // (1/8) * log2(e): flash softmax runs in exp2 domain

typedef short s16x8 __attribute__((ext_vector_type(8)));
typedef float f32x4 __attribute__((ext_vector_type(4)));
typedef unsigned short u16;
typedef unsigned int u32;

__device__ __forceinline__ u16 f2b(float f) {
  __hip_bfloat16 h = __float2bfloat16(f);
  return *reinterpret_cast<u16*>(&h);
}
__device__ __forceinline__ float b2f(u16 u) {
  __hip_bfloat16 h;
  *reinterpret_cast<u16*>(&h) = u;
  return __bfloat162float(h);
}
// pack two fp32 -> (bf16(hi)<<16)|bf16(lo) by truncation: ONE v_perm_b32
__device__ __forceinline__ u32 pkbf(float hi, float lo) {
  return __builtin_amdgcn_perm(__float_as_uint(hi), __float_as_uint(lo), 0x07060302u);
}

// async global->LDS, 16B per lane; LDS dest = wave-uniform base + lane*16
#define GLDS(g, l)                                                             \
  __builtin_amdgcn_global_load_lds(                                            \
      (const __attribute__((address_space(1))) unsigned int*)(g),              \
      (__attribute__((address_space(3))) unsigned int*)(l), 16, 0, 0)

// XOR-swizzle for [rows][64] u16 tiles, 16B-chunk granular
__device__ __forceinline__ int SW64(int row, int col) {
  return row * 64 + ((((col >> 3) ^ (row & 7) ^ (row >> 3)) & 7) << 3) + (col & 7);
}

// ---------------------------------------------------------------- casts + rope table, one launch
__global__ __launch_bounds__(256) void k_castall(
    const float* __restrict__ x,  const float* __restrict__ Wq,
    const float* __restrict__ Wk, const float* __restrict__ Wv,
    const float* __restrict__ Wo,
    u16* __restrict__ xb,  u16* __restrict__ wqb, u16* __restrict__ wkb,
    u16* __restrict__ wvb, u16* __restrict__ wob,
    const int* __restrict__ pos, float2* __restrict__ tab) {
  if (blockIdx.x >= 8192) {
    int t = (blockIdx.x - 8192) * 256 + threadIdx.x;   // 65536
    int s = t >> 5, i = t & 31;
    float p = (float)pos[s];
    // 10000^(-i/32) = exp2(-i * log2(10000)/32): one trans op, no libm powf
    float ang = p * __builtin_amdgcn_exp2f(-(float)i * 0.4152448120604907f);
    tab[t] = make_float2(cosf(ang), sinf(ang));
    return;
  }
  int i = blockIdx.x * 256 + threadIdx.x;        // 2M float4 total
  const float* s;
  u16* d;
  int off;
  if (i < 1048576) { s = x; d = xb; off = i; }
  else {
    int j = i - 1048576;
    int w = j >> 18;
    off = j & 262143;
    s = (w == 0) ? Wq : (w == 1) ? Wk : (w == 2) ? Wv : Wo;
    d = (w == 0) ? wqb : (w == 1) ? wkb : (w == 2) ? wvb : wob;
  }
  float4 v = reinterpret_cast<const float4*>(s)[off];
  ushort4 o;
  o.x = f2b(v.x); o.y = f2b(v.y); o.z = f2b(v.z); o.w = f2b(v.w);
  reinterpret_cast<ushort4*>(d)[off] = o;
}

// ---------------------------------------------------------------- RoPE apply on K only
__global__ __launch_bounds__(256) void k_ropeK(u16* __restrict__ K,
                                               const float2* __restrict__ tab) {
  int t = blockIdx.x * 256 + threadIdx.x;        // Mrows*Dm/8
  int row = t >> 7;
  int c0 = (t & 127) << 3;
  int i0 = (c0 & 63) >> 1;
  const float2* tb = &tab[(row & (Ss - 1)) * 32 + i0];
  float2 cs[4];
#pragma unroll
  for (int j = 0; j < 4; ++j) cs[j] = tb[j];
  size_t off = (size_t)row * Dm + c0;
  s16x8 k = *reinterpret_cast<const s16x8*>(&K[off]);
  s16x8 ko;
#pragma unroll
  for (int j = 0; j < 4; ++j) {
    float ke = b2f((u16)k[2 * j]), kd = b2f((u16)k[2 * j + 1]);
    ko[2 * j]     = (short)f2b(cs[j].x * ke - cs[j].y * kd);
    ko[2 * j + 1] = (short)f2b(cs[j].y * ke + cs[j].x * kd);
  }
  *reinterpret_cast<s16x8*>(&K[off]) = ko;
}

// ---------------------------------------------------------------- C = A * B^T
// 128xBN tile, BK=32. RING-3 LDS + depth-2 prefetch + COUNTED vmcnt (T4):
// per K-step, wait vmcnt(LOADS) (retires tile t, leaves tile t+1 in flight),
// raw s_barrier (no compiler vmcnt(0) drain), issue tile t+2's GLDS, then
// ds_read + MFMA. (r6-proven: QKV <46us. r9 lesson: NEVER perturb this main
// loop.)
// XCD-CHUNKED 1D GRID (r10 theory): FETCH was 40MB vs 14MB unique inputs —
// every XCD's ~96 co-resident blocks spanned ALL n-tiles, so the whole B
// matrix (6MB) thrashed each 4MB L2. Now xcd=bid&7 owns a contiguous slab of
// NXT/8 n-tiles: per-XCD B working set 768KB/512KB -> L2-resident, staging
// loads return at L2 latency which depth-2 prefetch fully covers.
// LDS: BN=128 48 KB -> 3 blocks/CU; BN=64 36 KB -> 4 blocks/CU.
template <int BN, bool QKV>
__global__ __launch_bounds__(256) void k_gemm(
    const u16* __restrict__ A, const u16* __restrict__ B,
    u16* __restrict__ OQ, u16* __restrict__ OK2, u16* __restrict__ OVT,
    float* __restrict__ OF, int K) {
  constexpr int NFR = BN / 32;
  __shared__ __align__(16) u16 lsA[3][128 * 32];
  __shared__ __align__(16) u16 lsB[3][BN * 32];
  const int tid = threadIdx.x, lane = tid & 63, wave = tid >> 6;
  const int quad = lane >> 4, l16 = lane & 15;
  const int wrow = wave >> 1, wcol = wave & 1;
  // XCD-chunked swizzle: grid = NXT*32 (1D, %8==0). xcd owns NXT/8 n-tiles.
  const int NXT = gridDim.x >> 5;              // 24 (QKV) or 16 (out-proj)
  const int xcd = blockIdx.x & 7, idx = blockIdx.x >> 3;
  const int n0 = (xcd * (NXT >> 3) + (idx >> 5)) * BN;
  const int m0 = (idx & 31) * 128;
  f32x4 acc[4][NFR] = {};

  auto stage = [&](int k0, int bi) {
    // A tile 128x32: 512 16B chunks, 2 per thread
#pragma unroll
    for (int c = 0; c < 2; ++c) {
      int f = (wave * 2 + c) * 64 + lane;
      int row = f >> 2;
      int gs = (f & 3) ^ ((row >> 1) & 3);
      GLDS(A + (size_t)(m0 + row) * K + k0 + gs * 8, &lsA[bi][(wave * 2 + c) * 512]);
    }
    // B tile BNx32: BN*4 chunks, NFR/2 per thread
#pragma unroll
    for (int c = 0; c < NFR / 2; ++c) {
      int f = (wave * (NFR / 2) + c) * 64 + lane;
      int row = f >> 2;
      int gs = (f & 3) ^ ((row >> 1) & 3);
      GLDS(B + (size_t)(n0 + row) * K + k0 + gs * 8, &lsB[bi][(wave * (NFR / 2) + c) * 512]);
    }
  };

  stage(0, 0);
  stage(32, 1);
  int bi = 0, stg = 2;
  for (int k0 = 0; k0 < K; k0 += 32) {
    if (k0 + 32 < K) {
      // retire tile t (its LOADS=2+NFR/2 GLDS per thread), keep t+1 in flight
      if constexpr (NFR == 4) asm volatile("s_waitcnt vmcnt(4)" ::: "memory");
      else                    asm volatile("s_waitcnt vmcnt(3)" ::: "memory");
    } else {
      asm volatile("s_waitcnt vmcnt(0)" ::: "memory");
    }
    __builtin_amdgcn_sched_barrier(0);
    __builtin_amdgcn_s_barrier();
    if (k0 + 64 < K) stage(k0 + 64, stg);
    s16x8 af[4], bfr[NFR];
#pragma unroll
    for (int i = 0; i < 4; ++i) {
      int row = wrow * 64 + i * 16 + l16;
      af[i] = *reinterpret_cast<const s16x8*>(
          &lsA[bi][row * 32 + ((quad ^ ((row >> 1) & 3)) << 3)]);
    }
#pragma unroll
    for (int i = 0; i < NFR; ++i) {
      int row = wcol * (BN / 2) + i * 16 + l16;
      bfr[i] = *reinterpret_cast<const s16x8*>(
          &lsB[bi][row * 32 + ((quad ^ ((row >> 1) & 3)) << 3)]);
    }
#pragma unroll
    for (int mi = 0; mi < 4; ++mi)
#pragma unroll
      for (int ni = 0; ni < NFR; ++ni)
        acc[mi][ni] = __builtin_amdgcn_mfma_f32_16x16x32_bf16(af[mi], bfr[ni], acc[mi][ni], 0, 0, 0);
    stg = bi;
    bi = (bi == 2) ? 0 : bi + 1;
  }

  if (QKV) {
    const int which = n0 >> 10;          // tiles never straddle a 1024 boundary
    const int nbase = (n0 & 1023) + wcol * (BN / 2);
    if (which == 2) {
#pragma unroll
      for (int mi = 0; mi < 4; ++mi)
#pragma unroll
        for (int ni = 0; ni < NFR; ++ni) {
          int row0 = m0 + wrow * 64 + mi * 16 + quad * 4;
          int col  = nbase + ni * 16 + l16;
          int bb = row0 >> 11, s0 = row0 & (Ss - 1);
          ushort4 pk;
          pk.x = f2b(acc[mi][ni][0]); pk.y = f2b(acc[mi][ni][1]);
          pk.z = f2b(acc[mi][ni][2]); pk.w = f2b(acc[mi][ni][3]);
          *reinterpret_cast<ushort4*>(&OVT[((size_t)bb * Dm + col) * Ss + s0]) = pk;
        }
    } else {
      u16* Op = which ? OK2 : OQ;
#pragma unroll
      for (int mi = 0; mi < 4; ++mi)
#pragma unroll
        for (int ni = 0; ni < NFR; ++ni)
#pragma unroll
          for (int r = 0; r < 4; ++r) {
            int row = m0 + wrow * 64 + mi * 16 + quad * 4 + r;
            int col = nbase + ni * 16 + l16;
            Op[(size_t)row * Dm + col] = f2b(acc[mi][ni][r]);
          }
    }
  } else {
#pragma unroll
    for (int mi = 0; mi < 4; ++mi)
#pragma unroll
      for (int ni = 0; ni < NFR; ++ni)
#pragma unroll
        for (int r = 0; r < 4; ++r) {
          int row = m0 + wrow * 64 + mi * 16 + quad * 4 + r;
          int col = n0 + wcol * (BN / 2) + ni * 16 + l16;
          OF[(size_t)row * Dm + col] = acc[mi][ni][r];
        }
  }
}

// ---------------------------------------------------------------- flash attention (causal)
// Transposed compute: S^T = K Q^T, O^T = V^T P^T. Static-max softmax, exp2
// domain, Q-RoPE fused into the fragment load. 16 q/wave, QBLK=64 (4 waves),
// grid 1024 blocks, 40 KB LDS -> 4 blocks/CU. (r8-proven 45.5us; four
// structural variants all ~46us — do not touch without a full reschedule.)
__global__ __launch_bounds__(256) void k_flash(const u16* __restrict__ Q,
                                               const u16* __restrict__ K,
                                               const u16* __restrict__ VT,
                                               u16* __restrict__ O,
                                               const float2* __restrict__ tab) {
  __shared__ __align__(16) u16 lsK[2][64 * 64];    // [slot][key][dk], SW64
  __shared__ __align__(16) u16 lsVT[2][64 * 64];   // [slot][dk][key], SW64
  __shared__ __align__(16) u16 lsP[4][16 * 64];    // per-wave P^T [q][key], chunk-xor
  const int tid = threadIdx.x, lane = tid & 63, wave = tid >> 6;
  const int quad = lane >> 4, l16 = lane & 15;
  const int bid = blockIdx.x;                      // 1024 blocks
  const int bh = bid & 31;
  const int h = bh & (H_ - 1), b = bh >> 4;
  const int g = bid >> 5, a = g & 15, bsel = g >> 4;
  const int qt = bsel ? (31 - a) : a;              // balanced causal map (64-q tiles)
  const int qbase = qt * 64 + wave * 16;
  const int xorv = (l16 * 2) & 0xE;

  // Q frag with fused RoPE (+QSCALE): q row = qbase+l16, 8 dk per kc chunk
  s16x8 qf[2];
  {
    const int qpos = qbase + l16;
    const size_t qoff = (size_t)(b * Ss + qpos) * Dm + h * 64;
    s16x8 r0 = *reinterpret_cast<const s16x8*>(&Q[qoff + quad * 8]);
    s16x8 r1 = *reinterpret_cast<const s16x8*>(&Q[qoff + 32 + quad * 8]);
    const float2* tb = &tab[qpos * 32];
#pragma unroll
    for (int kc = 0; kc < 2; ++kc) {
      s16x8 raw = kc ? r1 : r0;
#pragma unroll
      for (int p = 0; p < 4; ++p) {
        float2 cs = tb[kc * 16 + quad * 4 + p];
        float e = b2f((u16)raw[2 * p]), o = b2f((u16)raw[2 * p + 1]);
        qf[kc][2 * p]     = (short)f2b((cs.x * e - cs.y * o) * QSCALE);
        qf[kc][2 * p + 1] = (short)f2b((cs.y * e + cs.x * o) * QSCALE);
      }
    }
  }
  s16x8 ones;
#pragma unroll
  for (int j = 0; j < 8; ++j) ones[j] = (short)0x3F80;   // bf16 1.0

  f32x4 ot[4] = {};
  f32x4 lAcc = {};

  auto stage1 = [&](int kt) {
    const int slot = kt & 1;
    const size_t kbase  = (size_t)(b * Ss + kt * 64) * Dm + h * 64;
    const size_t vtbase = ((size_t)b * Dm + h * 64) * Ss + kt * 64;
#pragma unroll
    for (int c = 0; c < 2; ++c) {
      int sl = (wave * 2 + c) * 64 + lane;
      int row = sl >> 3;
      int gg = ((sl & 7) ^ (row & 7) ^ (row >> 3)) & 7;
      GLDS(K  + kbase  + (size_t)row * Dm + gg * 8, &lsK[slot][(wave * 2 + c) * 512]);
      GLDS(VT + vtbase + (size_t)row * Ss + gg * 8, &lsVT[slot][(wave * 2 + c) * 512]);
    }
  };

  const int ktend = qt + 1;
  stage1(0);
  for (int kt = 0; kt < ktend; ++kt) {
    __syncthreads();
    if (kt + 1 < ktend) stage1(kt + 1);
    const int slot = kt & 1;

    f32x4 st[4] = {};
#pragma unroll
    for (int kc = 0; kc < 2; ++kc)
#pragma unroll
      for (int ni = 0; ni < 4; ++ni) {
        s16x8 kf = *reinterpret_cast<const s16x8*>(
            &lsK[slot][SW64(ni * 16 + l16, kc * 32 + quad * 8)]);
        st[ni] = __builtin_amdgcn_mfma_f32_16x16x32_bf16(kf, qf[kc], st[ni], 0, 0, 0);
      }

    if (kt == qt) {   // diagonal tile (wave-uniform): mask key > q
      int gq = qbase + l16;
#pragma unroll
      for (int ni = 0; ni < 4; ++ni)
#pragma unroll
        for (int r = 0; r < 4; ++r)
          if (kt * 64 + ni * 16 + quad * 4 + r > gq) st[ni][r] = -INFINITY;
    }
#pragma unroll
    for (int ni = 0; ni < 4; ++ni) {
      float e0 = __builtin_amdgcn_exp2f(st[ni][0]);
      float e1 = __builtin_amdgcn_exp2f(st[ni][1]);
      float e2 = __builtin_amdgcn_exp2f(st[ni][2]);
      float e3 = __builtin_amdgcn_exp2f(st[ni][3]);
      uint2 pk;
      pk.x = pkbf(e1, e0);
      pk.y = pkbf(e3, e2);
      *reinterpret_cast<uint2*>(
          &lsP[wave][l16 * 64 + (((ni * 4 + quad) ^ xorv) << 2)]) = pk;
    }
#pragma unroll
    for (int kc = 0; kc < 2; ++kc) {
      s16x8 pf = *reinterpret_cast<const s16x8*>(
          &lsP[wave][l16 * 64 + (((kc * 8 + quad * 2) ^ xorv) << 2)]);
      lAcc = __builtin_amdgcn_mfma_f32_16x16x32_bf16(ones, pf, lAcc, 0, 0, 0);
#pragma unroll
      for (int ni = 0; ni < 4; ++ni) {
        s16x8 vf = *reinterpret_cast<const s16x8*>(
            &lsVT[slot][SW64(ni * 16 + l16, kc * 32 + quad * 8)]);
        ot[ni] = __builtin_amdgcn_mfma_f32_16x16x32_bf16(vf, pf, ot[ni], 0, 0, 0);
      }
    }
  }

  // epilogue: O[q][dk], 4 consecutive dk per lane -> 8B stores
  {
    float inv = 1.0f / lAcc[0];
    const size_t obase = (size_t)(b * Ss + qbase + l16) * Dm + h * 64;
#pragma unroll
    for (int ni = 0; ni < 4; ++ni) {
      ushort4 pk;
      pk.x = f2b(ot[ni][0] * inv); pk.y = f2b(ot[ni][1] * inv);
      pk.z = f2b(ot[ni][2] * inv); pk.w = f2b(ot[ni][3] * inv);
      *reinterpret_cast<ushort4*>(&O[obase + ni * 16 + quad * 4]) = pk;
    }
  }
}

// ---------------------------------------------------------------- launch
extern "C" void kernel_launch(void* const* d_in, const int* in_sizes, int n_in,
                              void* d_out, int out_size, void* d_ws, size_t ws_size,
                              hipStream_t stream) {
  const float* x  = (const float*)d_in[0];
  const float* Wq = (const float*)d_in[1];
  const float* Wk = (const float*)d_in[2];
  const float* Wv = (const float*)d_in[3];
  const float* Wo = (const float*)d_in[4];
  const int* pos  = (const int*)d_in[5];
  float* out = (float*)d_out;

  char* w = (char*)d_ws;
  u16* xb  = (u16*)w; w += (size_t)Mrows * Dm * 2;
  u16* wqb = (u16*)w; w += (size_t)Dm * Dm * 2;   // wqb/wkb/wvb contiguous:
  u16* wkb = (u16*)w; w += (size_t)Dm * Dm * 2;   // merged [3072][1024] B matrix
  u16* wvb = (u16*)w; w += (size_t)Dm * Dm * 2;
  u16* wob = (u16*)w; w += (size_t)Dm * Dm * 2;
  u16* Qb  = (u16*)w; w += (size_t)Mrows * Dm * 2;
  u16* Kb  = (u16*)w; w += (size_t)Mrows * Dm * 2;
  u16* VTb = (u16*)w; w += (size_t)Mrows * Dm * 2;   // V transposed [b][e][s]
  u16* Ab  = (u16*)w; w += (size_t)Mrows * Dm * 2;
  float2* tabf = (float2*)w; w += (size_t)Ss * 32 * sizeof(float2);

  // casts + rope table in one launch
  k_castall<<<8448, 256, 0, stream>>>(x, Wq, Wk, Wv, Wo, xb, wqb, wkb, wvb, wob,
                                      pos, tabf);
  // merged QKV projection: B=[3072][1024]; 1D grid, XCD-chunked swizzle inside
  k_gemm<128, true><<<768, 256, 0, stream>>>(xb, wqb, Qb, Kb, VTb, nullptr, Dm);
  // RoPE on K only (Q's RoPE fused into flash)
  k_ropeK<<<Mrows * Dm / 8 / 256, 256, 0, stream>>>(Kb, tabf);
  k_flash<<<dim3(1024), 256, 0, stream>>>(Qb, Kb, VTb, Ab, tabf);
  // output projection, fp32 epilogue; 1D grid, XCD-chunked swizzle inside
  k_gemm<64, false><<<512, 256, 0, stream>>>(Ab, wob, nullptr, nullptr, nullptr, out, Dm);
}

// Round 12
// 181.486 us; speedup vs baseline: 1.1956x; 1.0289x over previous
//
#include <hip/hip_runtime.h>
#include <hip/hip_bf16.h>
#include <math.h>

#define H_    16
#define DK_   64
#define Dm    1024
#define Bb    2
#define Ss    2048
#define Mrows 4096   // B*S
#define QSCALE 0.1803368801f   // (1/8) * log2(e): flash softmax runs in exp2 domain

typedef short s16x8 __attribute__((ext_vector_type(8)));
typedef float f32x4 __attribute__((ext_vector_type(4)));
typedef unsigned short u16;
typedef unsigned int u32;

__device__ __forceinline__ u16 f2b(float f) {
  __hip_bfloat16 h = __float2bfloat16(f);
  return *reinterpret_cast<u16*>(&h);
}
__device__ __forceinline__ float b2f(u16 u) {
  __hip_bfloat16 h;
  *reinterpret_cast<u16*>(&h) = u;
  return __bfloat162float(h);
}
// pack two fp32 -> (bf16(hi)<<16)|bf16(lo) by truncation: ONE v_perm_b32
__device__ __forceinline__ u32 pkbf(float hi, float lo) {
  return __builtin_amdgcn_perm(__float_as_uint(hi), __float_as_uint(lo), 0x07060302u);
}

// async global->LDS, 16B per lane; LDS dest = wave-uniform base + lane*16
#define GLDS(g, l)                                                             \
  __builtin_amdgcn_global_load_lds(                                            \
      (const __attribute__((address_space(1))) unsigned int*)(g),              \
      (__attribute__((address_space(3))) unsigned int*)(l), 16, 0, 0)

// XOR-swizzle for [rows][64] u16 tiles, 16B-chunk granular
__device__ __forceinline__ int SW64(int row, int col) {
  return row * 64 + ((((col >> 3) ^ (row & 7) ^ (row >> 3)) & 7) << 3) + (col & 7);
}

// ---------------------------------------------------------------- casts + rope table, one launch
__global__ __launch_bounds__(256) void k_castall(
    const float* __restrict__ x,  const float* __restrict__ Wq,
    const float* __restrict__ Wk, const float* __restrict__ Wv,
    const float* __restrict__ Wo,
    u16* __restrict__ xb,  u16* __restrict__ wqb, u16* __restrict__ wkb,
    u16* __restrict__ wvb, u16* __restrict__ wob,
    const int* __restrict__ pos, float2* __restrict__ tab) {
  if (blockIdx.x >= 8192) {
    int t = (blockIdx.x - 8192) * 256 + threadIdx.x;   // 65536
    int s = t >> 5, i = t & 31;
    float p = (float)pos[s];
    // 10000^(-i/32) = exp2(-i * log2(10000)/32): one trans op, no libm powf
    float ang = p * __builtin_amdgcn_exp2f(-(float)i * 0.4152448120604907f);
    tab[t] = make_float2(cosf(ang), sinf(ang));
    return;
  }
  int i = blockIdx.x * 256 + threadIdx.x;        // 2M float4 total
  const float* s;
  u16* d;
  int off;
  if (i < 1048576) { s = x; d = xb; off = i; }
  else {
    int j = i - 1048576;
    int w = j >> 18;
    off = j & 262143;
    s = (w == 0) ? Wq : (w == 1) ? Wk : (w == 2) ? Wv : Wo;
    d = (w == 0) ? wqb : (w == 1) ? wkb : (w == 2) ? wvb : wob;
  }
  float4 v = reinterpret_cast<const float4*>(s)[off];
  ushort4 o;
  o.x = f2b(v.x); o.y = f2b(v.y); o.z = f2b(v.z); o.w = f2b(v.w);
  reinterpret_cast<ushort4*>(d)[off] = o;
}

// ---------------------------------------------------------------- RoPE apply on K only
__global__ __launch_bounds__(256) void k_ropeK(u16* __restrict__ K,
                                               const float2* __restrict__ tab) {
  int t = blockIdx.x * 256 + threadIdx.x;        // Mrows*Dm/8
  int row = t >> 7;
  int c0 = (t & 127) << 3;
  int i0 = (c0 & 63) >> 1;
  const float2* tb = &tab[(row & (Ss - 1)) * 32 + i0];
  float2 cs[4];
#pragma unroll
  for (int j = 0; j < 4; ++j) cs[j] = tb[j];
  size_t off = (size_t)row * Dm + c0;
  s16x8 k = *reinterpret_cast<const s16x8*>(&K[off]);
  s16x8 ko;
#pragma unroll
  for (int j = 0; j < 4; ++j) {
    float ke = b2f((u16)k[2 * j]), kd = b2f((u16)k[2 * j + 1]);
    ko[2 * j]     = (short)f2b(cs[j].x * ke - cs[j].y * kd);
    ko[2 * j + 1] = (short)f2b(cs[j].y * ke + cs[j].x * kd);
  }
  *reinterpret_cast<s16x8*>(&K[off]) = ko;
}

// ---------------------------------------------------------------- C = A * B^T
// 128xBN tile, BK=32. RING-3 LDS + depth-2 prefetch + COUNTED vmcnt (T4):
// per K-step, wait vmcnt(LOADS) (retires tile t, leaves tile t+1 in flight),
// raw s_barrier (no compiler vmcnt(0) drain), issue tile t+2's GLDS, then
// ds_read + MFMA. (r6-proven: QKV <46us. r9 lesson: NEVER perturb this main
// loop.)
// XCD-chunked 1D grid (r10): xcd=bid&7 owns a contiguous slab of NXT/8
// n-tiles -> per-XCD B working set L2-resident. (r11: neutral in wall time,
// kept at zero cost.)
// LDS: BN=128 48 KB -> 3 blocks/CU; BN=64 36 KB -> 4 blocks/CU.
template <int BN, bool QKV>
__global__ __launch_bounds__(256) void k_gemm(
    const u16* __restrict__ A, const u16* __restrict__ B,
    u16* __restrict__ OQ, u16* __restrict__ OK2, u16* __restrict__ OVT,
    float* __restrict__ OF, int K) {
  constexpr int NFR = BN / 32;
  __shared__ __align__(16) u16 lsA[3][128 * 32];
  __shared__ __align__(16) u16 lsB[3][BN * 32];
  const int tid = threadIdx.x, lane = tid & 63, wave = tid >> 6;
  const int quad = lane >> 4, l16 = lane & 15;
  const int wrow = wave >> 1, wcol = wave & 1;
  // XCD-chunked swizzle: grid = NXT*32 (1D, %8==0). xcd owns NXT/8 n-tiles.
  const int NXT = gridDim.x >> 5;              // 24 (QKV) or 16 (out-proj)
  const int xcd = blockIdx.x & 7, idx = blockIdx.x >> 3;
  const int n0 = (xcd * (NXT >> 3) + (idx >> 5)) * BN;
  const int m0 = (idx & 31) * 128;
  f32x4 acc[4][NFR] = {};

  auto stage = [&](int k0, int bi) {
    // A tile 128x32: 512 16B chunks, 2 per thread
#pragma unroll
    for (int c = 0; c < 2; ++c) {
      int f = (wave * 2 + c) * 64 + lane;
      int row = f >> 2;
      int gs = (f & 3) ^ ((row >> 1) & 3);
      GLDS(A + (size_t)(m0 + row) * K + k0 + gs * 8, &lsA[bi][(wave * 2 + c) * 512]);
    }
    // B tile BNx32: BN*4 chunks, NFR/2 per thread
#pragma unroll
    for (int c = 0; c < NFR / 2; ++c) {
      int f = (wave * (NFR / 2) + c) * 64 + lane;
      int row = f >> 2;
      int gs = (f & 3) ^ ((row >> 1) & 3);
      GLDS(B + (size_t)(n0 + row) * K + k0 + gs * 8, &lsB[bi][(wave * (NFR / 2) + c) * 512]);
    }
  };

  stage(0, 0);
  stage(32, 1);
  int bi = 0, stg = 2;
  for (int k0 = 0; k0 < K; k0 += 32) {
    if (k0 + 32 < K) {
      // retire tile t (its LOADS=2+NFR/2 GLDS per thread), keep t+1 in flight
      if constexpr (NFR == 4) asm volatile("s_waitcnt vmcnt(4)" ::: "memory");
      else                    asm volatile("s_waitcnt vmcnt(3)" ::: "memory");
    } else {
      asm volatile("s_waitcnt vmcnt(0)" ::: "memory");
    }
    __builtin_amdgcn_sched_barrier(0);
    __builtin_amdgcn_s_barrier();
    if (k0 + 64 < K) stage(k0 + 64, stg);
    s16x8 af[4], bfr[NFR];
#pragma unroll
    for (int i = 0; i < 4; ++i) {
      int row = wrow * 64 + i * 16 + l16;
      af[i] = *reinterpret_cast<const s16x8*>(
          &lsA[bi][row * 32 + ((quad ^ ((row >> 1) & 3)) << 3)]);
    }
#pragma unroll
    for (int i = 0; i < NFR; ++i) {
      int row = wcol * (BN / 2) + i * 16 + l16;
      bfr[i] = *reinterpret_cast<const s16x8*>(
          &lsB[bi][row * 32 + ((quad ^ ((row >> 1) & 3)) << 3)]);
    }
#pragma unroll
    for (int mi = 0; mi < 4; ++mi)
#pragma unroll
      for (int ni = 0; ni < NFR; ++ni)
        acc[mi][ni] = __builtin_amdgcn_mfma_f32_16x16x32_bf16(af[mi], bfr[ni], acc[mi][ni], 0, 0, 0);
    stg = bi;
    bi = (bi == 2) ? 0 : bi + 1;
  }

  if (QKV) {
    const int which = n0 >> 10;          // tiles never straddle a 1024 boundary
    const int nbase = (n0 & 1023) + wcol * (BN / 2);
    if (which == 2) {
#pragma unroll
      for (int mi = 0; mi < 4; ++mi)
#pragma unroll
        for (int ni = 0; ni < NFR; ++ni) {
          int row0 = m0 + wrow * 64 + mi * 16 + quad * 4;
          int col  = nbase + ni * 16 + l16;
          int bb = row0 >> 11, s0 = row0 & (Ss - 1);
          ushort4 pk;
          pk.x = f2b(acc[mi][ni][0]); pk.y = f2b(acc[mi][ni][1]);
          pk.z = f2b(acc[mi][ni][2]); pk.w = f2b(acc[mi][ni][3]);
          *reinterpret_cast<ushort4*>(&OVT[((size_t)bb * Dm + col) * Ss + s0]) = pk;
        }
    } else {
      u16* Op = which ? OK2 : OQ;
#pragma unroll
      for (int mi = 0; mi < 4; ++mi)
#pragma unroll
        for (int ni = 0; ni < NFR; ++ni)
#pragma unroll
          for (int r = 0; r < 4; ++r) {
            int row = m0 + wrow * 64 + mi * 16 + quad * 4 + r;
            int col = nbase + ni * 16 + l16;
            Op[(size_t)row * Dm + col] = f2b(acc[mi][ni][r]);
          }
    }
  } else {
#pragma unroll
    for (int mi = 0; mi < 4; ++mi)
#pragma unroll
      for (int ni = 0; ni < NFR; ++ni)
#pragma unroll
        for (int r = 0; r < 4; ++r) {
          int row = m0 + wrow * 64 + mi * 16 + quad * 4 + r;
          int col = n0 + wcol * (BN / 2) + ni * 16 + l16;
          OF[(size_t)row * Dm + col] = acc[mi][ni][r];
        }
  }
}

// ---------------------------------------------------------------- flash attention (causal)
// Transposed compute: S^T = K Q^T, O^T = V^T P^T. Static-max softmax, exp2
// domain, Q-RoPE fused into the fragment load. 16 q/wave, QBLK=64 (4 waves),
// grid 1024 blocks, 40 KB LDS -> 4 blocks/CU.
//
// XCD-grouped (b,h) [r11 theory]: old bh=bid&31 spread all 32 heads across
// every XCD -> per-XCD K/V working set 16MB >> 4MB L2, GLDS returned at
// L3/HBM latency (~450-900cy) and the per-kt barrier exposed it. Now
// xcd=bid&7 owns bh in [4*xcd, 4*xcd+4): per-XCD K/V = 2MB, L2-RESIDENT.
// qt balanced: CU's 4 blocks (round-robin by idx) sum to 66 work-units.
__global__ __launch_bounds__(256) void k_flash(const u16* __restrict__ Q,
                                               const u16* __restrict__ K,
                                               const u16* __restrict__ VT,
                                               u16* __restrict__ O,
                                               const float2* __restrict__ tab) {
  __shared__ __align__(16) u16 lsK[2][64 * 64];    // [slot][key][dk], SW64
  __shared__ __align__(16) u16 lsVT[2][64 * 64];   // [slot][dk][key], SW64
  __shared__ __align__(16) u16 lsP[4][16 * 64];    // per-wave P^T [q][key], chunk-xor
  const int tid = threadIdx.x, lane = tid & 63, wave = tid >> 6;
  const int quad = lane >> 4, l16 = lane & 15;
  const int bid = blockIdx.x;                      // 1024 blocks
  const int xcd = bid & 7, idx = bid >> 3;
  const int bh = xcd * 4 + (idx & 3);              // XCD-grouped head
  const int h = bh & (H_ - 1), b = bh >> 4;
  const int i2 = idx >> 2;                         // 0..31
  const int qt = (i2 < 16) ? i2 : 47 - i2;         // balanced causal map
  const int qbase = qt * 64 + wave * 16;
  const int xorv = (l16 * 2) & 0xE;

  // Q frag with fused RoPE (+QSCALE): q row = qbase+l16, 8 dk per kc chunk
  s16x8 qf[2];
  {
    const int qpos = qbase + l16;
    const size_t qoff = (size_t)(b * Ss + qpos) * Dm + h * 64;
    s16x8 r0 = *reinterpret_cast<const s16x8*>(&Q[qoff + quad * 8]);
    s16x8 r1 = *reinterpret_cast<const s16x8*>(&Q[qoff + 32 + quad * 8]);
    const float2* tb = &tab[qpos * 32];
#pragma unroll
    for (int kc = 0; kc < 2; ++kc) {
      s16x8 raw = kc ? r1 : r0;
#pragma unroll
      for (int p = 0; p < 4; ++p) {
        float2 cs = tb[kc * 16 + quad * 4 + p];
        float e = b2f((u16)raw[2 * p]), o = b2f((u16)raw[2 * p + 1]);
        qf[kc][2 * p]     = (short)f2b((cs.x * e - cs.y * o) * QSCALE);
        qf[kc][2 * p + 1] = (short)f2b((cs.y * e + cs.x * o) * QSCALE);
      }
    }
  }
  s16x8 ones;
#pragma unroll
  for (int j = 0; j < 8; ++j) ones[j] = (short)0x3F80;   // bf16 1.0

  f32x4 ot[4] = {};
  f32x4 lAcc = {};

  auto stage1 = [&](int kt) {
    const int slot = kt & 1;
    const size_t kbase  = (size_t)(b * Ss + kt * 64) * Dm + h * 64;
    const size_t vtbase = ((size_t)b * Dm + h * 64) * Ss + kt * 64;
#pragma unroll
    for (int c = 0; c < 2; ++c) {
      int sl = (wave * 2 + c) * 64 + lane;
      int row = sl >> 3;
      int gg = ((sl & 7) ^ (row & 7) ^ (row >> 3)) & 7;
      GLDS(K  + kbase  + (size_t)row * Dm + gg * 8, &lsK[slot][(wave * 2 + c) * 512]);
      GLDS(VT + vtbase + (size_t)row * Ss + gg * 8, &lsVT[slot][(wave * 2 + c) * 512]);
    }
  };

  const int ktend = qt + 1;
  stage1(0);
  for (int kt = 0; kt < ktend; ++kt) {
    __syncthreads();
    if (kt + 1 < ktend) stage1(kt + 1);
    const int slot = kt & 1;

    f32x4 st[4] = {};
#pragma unroll
    for (int kc = 0; kc < 2; ++kc)
#pragma unroll
      for (int ni = 0; ni < 4; ++ni) {
        s16x8 kf = *reinterpret_cast<const s16x8*>(
            &lsK[slot][SW64(ni * 16 + l16, kc * 32 + quad * 8)]);
        st[ni] = __builtin_amdgcn_mfma_f32_16x16x32_bf16(kf, qf[kc], st[ni], 0, 0, 0);
      }

    if (kt == qt) {   // diagonal tile (wave-uniform): mask key > q
      int gq = qbase + l16;
#pragma unroll
      for (int ni = 0; ni < 4; ++ni)
#pragma unroll
        for (int r = 0; r < 4; ++r)
          if (kt * 64 + ni * 16 + quad * 4 + r > gq) st[ni][r] = -INFINITY;
    }
#pragma unroll
    for (int ni = 0; ni < 4; ++ni) {
      float e0 = __builtin_amdgcn_exp2f(st[ni][0]);
      float e1 = __builtin_amdgcn_exp2f(st[ni][1]);
      float e2 = __builtin_amdgcn_exp2f(st[ni][2]);
      float e3 = __builtin_amdgcn_exp2f(st[ni][3]);
      uint2 pk;
      pk.x = pkbf(e1, e0);
      pk.y = pkbf(e3, e2);
      *reinterpret_cast<uint2*>(
          &lsP[wave][l16 * 64 + (((ni * 4 + quad) ^ xorv) << 2)]) = pk;
    }
#pragma unroll
    for (int kc = 0; kc < 2; ++kc) {
      s16x8 pf = *reinterpret_cast<const s16x8*>(
          &lsP[wave][l16 * 64 + (((kc * 8 + quad * 2) ^ xorv) << 2)]);
      lAcc = __builtin_amdgcn_mfma_f32_16x16x32_bf16(ones, pf, lAcc, 0, 0, 0);
#pragma unroll
      for (int ni = 0; ni < 4; ++ni) {
        s16x8 vf = *reinterpret_cast<const s16x8*>(
            &lsVT[slot][SW64(ni * 16 + l16, kc * 32 + quad * 8)]);
        ot[ni] = __builtin_amdgcn_mfma_f32_16x16x32_bf16(vf, pf, ot[ni], 0, 0, 0);
      }
    }
  }

  // epilogue: O[q][dk], 4 consecutive dk per lane -> 8B stores
  {
    float inv = 1.0f / lAcc[0];
    const size_t obase = (size_t)(b * Ss + qbase + l16) * Dm + h * 64;
#pragma unroll
    for (int ni = 0; ni < 4; ++ni) {
      ushort4 pk;
      pk.x = f2b(ot[ni][0] * inv); pk.y = f2b(ot[ni][1] * inv);
      pk.z = f2b(ot[ni][2] * inv); pk.w = f2b(ot[ni][3] * inv);
      *reinterpret_cast<ushort4*>(&O[obase + ni * 16 + quad * 4]) = pk;
    }
  }
}

// ---------------------------------------------------------------- launch
extern "C" void kernel_launch(void* const* d_in, const int* in_sizes, int n_in,
                              void* d_out, int out_size, void* d_ws, size_t ws_size,
                              hipStream_t stream) {
  const float* x  = (const float*)d_in[0];
  const float* Wq = (const float*)d_in[1];
  const float* Wk = (const float*)d_in[2];
  const float* Wv = (const float*)d_in[3];
  const float* Wo = (const float*)d_in[4];
  const int* pos  = (const int*)d_in[5];
  float* out = (float*)d_out;

  char* w = (char*)d_ws;
  u16* xb  = (u16*)w; w += (size_t)Mrows * Dm * 2;
  u16* wqb = (u16*)w; w += (size_t)Dm * Dm * 2;   // wqb/wkb/wvb contiguous:
  u16* wkb = (u16*)w; w += (size_t)Dm * Dm * 2;   // merged [3072][1024] B matrix
  u16* wvb = (u16*)w; w += (size_t)Dm * Dm * 2;
  u16* wob = (u16*)w; w += (size_t)Dm * Dm * 2;
  u16* Qb  = (u16*)w; w += (size_t)Mrows * Dm * 2;
  u16* Kb  = (u16*)w; w += (size_t)Mrows * Dm * 2;
  u16* VTb = (u16*)w; w += (size_t)Mrows * Dm * 2;   // V transposed [b][e][s]
  u16* Ab  = (u16*)w; w += (size_t)Mrows * Dm * 2;
  float2* tabf = (float2*)w; w += (size_t)Ss * 32 * sizeof(float2);

  // casts + rope table in one launch
  k_castall<<<8448, 256, 0, stream>>>(x, Wq, Wk, Wv, Wo, xb, wqb, wkb, wvb, wob,
                                      pos, tabf);
  // merged QKV projection: B=[3072][1024]; 1D grid, XCD-chunked swizzle inside
  k_gemm<128, true><<<768, 256, 0, stream>>>(xb, wqb, Qb, Kb, VTb, nullptr, Dm);
  // RoPE on K only (Q's RoPE fused into flash)
  k_ropeK<<<Mrows * Dm / 8 / 256, 256, 0, stream>>>(Kb, tabf);
  k_flash<<<dim3(1024), 256, 0, stream>>>(Qb, Kb, VTb, Ab, tabf);
  // output projection, fp32 epilogue; 1D grid, XCD-chunked swizzle inside
  k_gemm<64, false><<<512, 256, 0, stream>>>(Ab, wob, nullptr, nullptr, nullptr, out, Dm);
}